// Round 1
// baseline (185.888 us; speedup 1.0000x reference)
//
#include <hip/hip_runtime.h>
#include <hip/hip_bf16.h>

// Problem dims (fixed by setup_inputs): B=16, A=9, H=56, W=56, N=64.
// Output: (B, A*H*W, N) fp32 IoU matrix.
// Mapping: one 64-lane wave per proposal; lane index = bbox index n.
// Output store is one fully-coalesced 256B dwordx1-per-lane store per wave.

constexpr int B_ = 16;
constexpr int A_ = 9;
constexpr int H_ = 56;
constexpr int W_ = 56;
constexpr int N_ = 64;
constexpr int HW_ = H_ * W_;          // 3136
constexpr int P_ = A_ * HW_;          // 28224 proposals per batch
constexpr int NPROP = B_ * P_;        // 451584 total proposals (= total waves)

__global__ __launch_bounds__(256) void ssd_iou_kernel(
    const float* __restrict__ anc,      // (A,2)
    const float* __restrict__ grid,     // (B,H,W,2)
    const float* __restrict__ offsets,  // (B,A,H,W,4)
    const float* __restrict__ bboxes,   // (B,N,5)
    float* __restrict__ out)            // (B, P, N)
{
    const int tid  = blockIdx.x * blockDim.x + threadIdx.x;
    const int wave = tid >> 6;   // proposal id (global)
    const int lane = tid & 63;   // bbox id
    if (wave >= NPROP) return;

    const int b  = wave / P_;
    const int p  = wave - b * P_;
    const int a  = p / HW_;
    const int hw = p - a * HW_;

    // Proposal decode (same for all 64 lanes; broadcast loads).
    // offsets flat float4 index == wave (layout (B,A,H,W,4)).
    const float4 off = reinterpret_cast<const float4*>(offsets)[wave];
    const float2 g   = reinterpret_cast<const float2*>(grid)[b * HW_ + hw];
    const float  aw  = anc[2 * a + 0];
    const float  ah  = anc[2 * a + 1];

    const float xc = g.x + off.x;
    const float yc = g.y + off.y;
    const float wp = aw * __expf(off.z);
    const float hp = ah * __expf(off.w);

    const float px0 = xc - 0.5f * wp;
    const float py0 = yc - 0.5f * hp;
    const float px1 = xc + 0.5f * wp;
    const float py1 = yc + 0.5f * hp;

    // Per-lane bbox (first 4 of 5 columns). 20KB total -> L1-resident.
    const float* bb = bboxes + ((size_t)(b * N_ + lane)) * 5;
    const float bx0 = bb[0];
    const float by0 = bb[1];
    const float bx1 = bb[2];
    const float by1 = bb[3];

    const float tlx = fmaxf(px0, bx0);
    const float tly = fmaxf(py0, by0);
    const float brx = fminf(px1, bx1);
    const float bry = fminf(py1, by1);

    const bool no_inter = (tlx > brx) || (tly > bry);
    float aoi = (brx - tlx) * (bry - tly);
    aoi = no_inter ? 0.0f : aoi;

    const float aop = (px1 - px0) * (py1 - py0);
    const float aob = (bx1 - bx0) * (by1 - by0);

    out[(size_t)wave * N_ + lane] = aoi / (aop + aob - aoi);
}

extern "C" void kernel_launch(void* const* d_in, const int* in_sizes, int n_in,
                              void* d_out, int out_size, void* d_ws, size_t ws_size,
                              hipStream_t stream) {
    const float* anc     = (const float*)d_in[0];
    const float* grid    = (const float*)d_in[1];
    const float* offsets = (const float*)d_in[2];
    const float* bboxes  = (const float*)d_in[3];
    float* out = (float*)d_out;

    const int total_threads = NPROP * 64;          // 28,901,376
    const int block = 256;
    const int nblocks = (total_threads + block - 1) / block;  // 112,896
    ssd_iou_kernel<<<nblocks, block, 0, stream>>>(anc, grid, offsets, bboxes, out);
}

// Round 2
// 136.888 us; speedup vs baseline: 1.3580x; 1.3580x over previous
//
#include <hip/hip_runtime.h>
#include <hip/hip_bf16.h>

// Problem dims (fixed by setup_inputs): B=16, A=9, H=56, W=56, N=64.
// Output: (B, A*H*W, N) fp32 IoU matrix.
//
// R1 design: two-phase block.
//   Phase 1: 192 threads decode 192 proposals (one batch each block) into LDS
//            as {x0,y0,x1,y1} float4 + precomputed proposal area.
//   Phase 2: each of the 3 waves owns 64 proposals; lane = bbox index.
//            Loop over proposals: broadcast ds_read_b128 of the box,
//            ~13 VALU for IoU (fmax-clamp instead of cmp/cndmask,
//            rcp*mul instead of precise divide), one coalesced 256B store.
// Block=192 because 28224 (proposals/batch) = 147*192 -> no batch straddle.

constexpr int B_ = 16;
constexpr int A_ = 9;
constexpr int H_ = 56;
constexpr int W_ = 56;
constexpr int N_ = 64;
constexpr int HW_ = H_ * W_;            // 3136
constexpr int P_ = A_ * HW_;            // 28224 proposals per batch
constexpr int BLOCK = 192;              // 3 waves
constexpr int BLKS_PER_BATCH = P_ / BLOCK;  // 147

__global__ __launch_bounds__(BLOCK) void ssd_iou_kernel(
    const float* __restrict__ anc,      // (A,2)
    const float* __restrict__ grid,     // (B,H,W,2)
    const float* __restrict__ offsets,  // (B,A,H,W,4)
    const float* __restrict__ bboxes,   // (B,N,5)
    float* __restrict__ out)            // (B, P, N)
{
    __shared__ float4 s_box[BLOCK];
    __shared__ float  s_aop[BLOCK];

    const int t  = threadIdx.x;
    const int b  = blockIdx.x / BLKS_PER_BATCH;           // batch (uniform)
    const int lb = blockIdx.x - b * BLKS_PER_BATCH;       // block within batch
    const int p0 = lb * BLOCK;                            // first local proposal

    // ---- Phase 1: decode one proposal per thread into LDS ----
    {
        const int lp = p0 + t;               // local proposal id in batch
        const int a  = lp / HW_;
        const int hw = lp - a * HW_;
        const int gp = b * P_ + lp;          // global proposal id

        const float4 off = reinterpret_cast<const float4*>(offsets)[gp];
        const float2 g   = reinterpret_cast<const float2*>(grid)[b * HW_ + hw];
        const float  aw  = anc[2 * a + 0];
        const float  ah  = anc[2 * a + 1];

        const float xc = g.x + off.x;
        const float yc = g.y + off.y;
        const float wp = aw * __expf(off.z);
        const float hp = ah * __expf(off.w);

        float4 box;
        box.x = xc - 0.5f * wp;   // x0
        box.y = yc - 0.5f * hp;   // y0
        box.z = xc + 0.5f * wp;   // x1
        box.w = yc + 0.5f * hp;   // y1
        s_box[t] = box;
        s_aop[t] = wp * hp;       // proposal area
    }
    __syncthreads();

    // ---- Phase 2: wave w handles proposals [w*64, w*64+64), lane = bbox ----
    const int wave = t >> 6;
    const int lane = t & 63;

    // Per-lane bbox (constant across the loop). 20KB total -> L1-resident.
    const float* bb = bboxes + ((size_t)(b * N_ + lane)) * 5;
    const float bx0 = bb[0];
    const float by0 = bb[1];
    const float bx1 = bb[2];
    const float by1 = bb[3];
    const float aob = (bx1 - bx0) * (by1 - by0);

    const int   pbase = wave * 64;
    float* orow = out + ((size_t)(b * P_ + p0 + pbase)) * N_ + lane;

    #pragma unroll 8
    for (int j = 0; j < 64; ++j) {
        const float4 pr  = s_box[pbase + j];
        const float  aop = s_aop[pbase + j];

        const float tlx = fmaxf(pr.x, bx0);
        const float tly = fmaxf(pr.y, by0);
        const float brx = fminf(pr.z, bx1);
        const float bry = fminf(pr.w, by1);

        const float iw  = fmaxf(brx - tlx, 0.0f);
        const float ih  = fmaxf(bry - tly, 0.0f);
        const float aoi = iw * ih;

        const float denom = aop + aob - aoi;
        const float iou   = aoi * __frcp_rn(denom);

        __builtin_nontemporal_store(iou, orow + (size_t)j * N_);
    }
}

extern "C" void kernel_launch(void* const* d_in, const int* in_sizes, int n_in,
                              void* d_out, int out_size, void* d_ws, size_t ws_size,
                              hipStream_t stream) {
    const float* anc     = (const float*)d_in[0];
    const float* grid    = (const float*)d_in[1];
    const float* offsets = (const float*)d_in[2];
    const float* bboxes  = (const float*)d_in[3];
    float* out = (float*)d_out;

    const int nblocks = B_ * BLKS_PER_BATCH;   // 2352
    ssd_iou_kernel<<<nblocks, BLOCK, 0, stream>>>(anc, grid, offsets, bboxes, out);
}